// Round 10
// baseline (439.657 us; speedup 1.0000x reference)
//
#include <hip/hip_runtime.h>
#include <hip/hip_bf16.h>

typedef __hip_bfloat16 bf16;
typedef __attribute__((ext_vector_type(8))) short short8;
typedef __attribute__((ext_vector_type(4))) float f32x4;

#define ROWS 8192   // B*N
#define NPTS 2048
#define CIN  128
#define COUT 256
#define KNN  32
#define PAD  132    // dist_feat LDS leading dim: 16B-aligned rows -> ds_read_b128 (PAD=129 regressed, R13)

__device__ inline float lrelu(float x){ return x >= 0.f ? x : 0.2f*x; }
__device__ inline unsigned short f2bf(float x){
  bf16 h = __float2bfloat16(x);
  return *(unsigned short*)&h;
}
__device__ inline float bf2f(unsigned short u){ return __uint_as_float((unsigned)u << 16); }
__device__ inline void stc(float* p, float v){ *p = v; }
__device__ inline void stc(unsigned short* p, float v){ *p = f2bf(v); }

// ---------------- fused one-time prep: WT_x, bcat, WT_ffn, WT_fc, feat_bf, pp(base_xyz) ----------------
#define N_WTX   (2048*CIN)          // 262144
#define N_WFFN  (2*COUT*COUT)       // 131072
#define N_WFC   (COUT*512)          // 131072
#define N_FEAT  (ROWS*CIN)          // 1048576
#define N_PP    8192                // 4 batches x 2048 base-point norms
__global__ __launch_bounds__(256) void pack_all(
    const float* qW, const float* kW, const float* vW, const float* rW,
    const float* qb, const float* kb, const float* vb, const float* rb,
    const float* ffnW, const float* fcW, const float* feature, const float* base_xyz,
    unsigned short* WT_x, float* bcat, unsigned short* WT_ffn,
    unsigned short* WT_fc, unsigned short* feat_bf, float* ppxyz){
  int t = blockIdx.x*256 + threadIdx.x;
  if (t < N_WTX){
    int c = t >> 7, r = t & 127;
    int g = c >> 8, i = g >> 2, tt = g & 3, cc = c & 255;
    const float* W = (tt==0?qW: tt==1?kW: tt==2?vW: rW) + (size_t)i*CIN*COUT;
    WT_x[t] = f2bf(W[r*COUT + cc]);
    if (r == 0){
      const float* bb = (tt==0?qb: tt==1?kb: tt==2?vb: rb) + i*COUT;
      bcat[c] = bb[cc];
    }
  } else if (t < N_WTX + N_WFFN){
    int u = t - N_WTX;
    int i = u >> 16, n = (u >> 8) & 255, k = u & 255;
    WT_ffn[u] = f2bf(ffnW[(size_t)i*65536 + k*256 + n]);
  } else if (t < N_WTX + N_WFFN + N_WFC){
    int u = t - N_WTX - N_WFFN;
    int n = u >> 9, k = u & 511;
    WT_fc[u] = f2bf(fcW[(size_t)k*256 + n]);
  } else if (t < N_WTX + N_WFFN + N_WFC + N_FEAT){
    int u = t - N_WTX - N_WFFN - N_WFC;
    feat_bf[u] = f2bf(feature[u]);
  } else {
    // base-point norms, frozen chain (identical to previous in-kernel computation)
    int u = t - N_WTX - N_WFFN - N_WFC - N_FEAT;   // exactly N_PP of these
    float p0 = base_xyz[(size_t)u*3+0];
    float p1 = base_xyz[(size_t)u*3+1];
    float p2 = base_xyz[(size_t)u*3+2];
    ppxyz[u] = __fadd_rn(__fadd_rn(__fmul_rn(p0,p0), __fmul_rn(p1,p1)), __fmul_rn(p2,p2));
  }
}

// ---------------- wave-parallel top-32, 32-bit keys, MODE1 ownership ----------------
// m = lane*32 + slot (lane owns 32 CONTIGUOUS indices, keys in registers).
// Key = monotone u32 transform of fp32 distance. Exact numpy tie-order (lowest m among
// equal dists) decomposes: ballot lowest LANE with min ✓ then owner's lowest SLOT ✓.
// Reduce = 4x v_min_u32+row_shr DPP (row_bcast is REMOVED on CDNA2+), 4x readlane +
// scalar min, ballot+ctz for owner. Sentinel 0xFFFFFFFF unreachable for finite inputs.
__device__ inline unsigned dxf(float d){
  unsigned u = __float_as_uint(d);
  return (u & 0x80000000u) ? ~u : (u | 0x80000000u);
}
__device__ inline unsigned umin32(unsigned a, unsigned b){ return a < b ? a : b; }

#define DPP_ROW_SHR1    0x111
#define DPP_ROW_SHR2    0x112
#define DPP_ROW_SHR4    0x114
#define DPP_ROW_SHR8    0x118

template<int CTRL>
__device__ inline unsigned dpp_umin_step(unsigned v){
  // bound_ctrl=false, old=own value: invalid lanes keep own -> min(v,v)=v
  unsigned s = (unsigned)__builtin_amdgcn_update_dpp((int)v, (int)v, CTRL, 0xF, 0xF, false);
  return s < v ? s : v;
}

#define TOPK32_CASE(G)                                                   \
  {                                                                      \
    int jw = 7;                                                          \
    _Pragma("unroll")                                                    \
    for (int j = 7; j >= 0; --j) if (k[G*8+j] == minv) jw = j;           \
    slot = G*8 + jw;                                                     \
    _Pragma("unroll")                                                    \
    for (int j = 0; j < 8; ++j) if (j == jw) k[G*8+j] = ~0u;             \
    unsigned nm = k[G*8];                                                \
    _Pragma("unroll")                                                    \
    for (int j = 1; j < 8; ++j) nm = umin32(nm, k[G*8+j]);               \
    g[G] = nm;                                                           \
  }

__device__ inline void wave_topk32_u32(unsigned* k, int lane, int* out){
  unsigned g[4];
  #pragma unroll
  for (int gi = 0; gi < 4; ++gi){
    unsigned m = k[gi*8];
    #pragma unroll
    for (int j = 1; j < 8; ++j) m = umin32(m, k[gi*8+j]);
    g[gi] = m;
  }
  unsigned outv = 0;
  for (int r = 0; r < KNN; ++r){
    unsigned lm = umin32(umin32(g[0], g[1]), umin32(g[2], g[3]));  // lane's own min
    unsigned m = lm;
    m = dpp_umin_step<DPP_ROW_SHR1>(m);
    m = dpp_umin_step<DPP_ROW_SHR2>(m);
    m = dpp_umin_step<DPP_ROW_SHR4>(m);
    m = dpp_umin_step<DPP_ROW_SHR8>(m);
    unsigned b0 = (unsigned)__builtin_amdgcn_readlane((int)m, 15);
    unsigned b1 = (unsigned)__builtin_amdgcn_readlane((int)m, 31);
    unsigned b2 = (unsigned)__builtin_amdgcn_readlane((int)m, 47);
    unsigned b3 = (unsigned)__builtin_amdgcn_readlane((int)m, 63);
    unsigned minv = umin32(umin32(b0, b1), umin32(b2, b3));        // wave-uniform
    unsigned long long ball = __ballot(lm == minv);
    int owner = (int)__builtin_ctzll(ball);                        // lowest tied lane = lowest m
    int slot = 0;
    if (owner == lane){
      int gw = (g[0]==minv) ? 0 : (g[1]==minv) ? 1 : (g[2]==minv) ? 2 : 3;  // lowest group
      if      (gw == 0) TOPK32_CASE(0)
      else if (gw == 1) TOPK32_CASE(1)
      else if (gw == 2) TOPK32_CASE(2)
      else              TOPK32_CASE(3)
    }
    int slotw = __builtin_amdgcn_readlane(slot, owner);            // wave-uniform
    unsigned wm = (unsigned)(owner*32 + slotw);
    outv = (lane == r) ? wm : outv;                                // lane r captures winner r
  }
  if (lane < KNN) out[lane] = (int)outv;
}

// ---------------- xyz KNN (frozen: numpy-faithful fp32, bit-exact) ----------------
// LDS-free, register-resident 32-bit keys; lane owns 32 contiguous points.
// pp loaded from precomputed table (pack_all, identical FP chain -> identical bits).
__device__ inline unsigned dkey_xyz(float qq, float q0, float q1, float q2,
                                    float p0, float p1, float p2, float pp){
  float dot = __fmul_rn(q0,p0);
  dot = __fadd_rn(dot, __fmul_rn(q1,p1));
  dot = __fadd_rn(dot, __fmul_rn(q2,p2));
  float d = __fsub_rn(__fadd_rn(qq, pp), __fmul_rn(2.f, dot));
  return dxf(d);
}

__global__ __launch_bounds__(256, 6) void knn_xyz_kernel(const float* xyz, const float* base,
                                                         const float* ppxyz, int* idx_out){
  int wave = threadIdx.x >> 6;
  int lane = threadIdx.x & 63;
  int bid = blockIdx.x*4 + wave;
  int b = bid >> 11;
  float q0 = xyz[(size_t)bid*3+0];
  float q1 = xyz[(size_t)bid*3+1];
  float q2 = xyz[(size_t)bid*3+2];
  float qq = __fadd_rn(__fadd_rn(__fmul_rn(q0,q0), __fmul_rn(q1,q1)), __fmul_rn(q2,q2));
  // lane's 32 points: m = lane*32 + (c*4 + j); 96 floats = 24 float4 per lane, 16B-aligned
  const float4* p4 = (const float4*)(base + (size_t)b*NPTS*3 + (size_t)lane*96);
  const float4* n4 = (const float4*)(ppxyz + (size_t)b*NPTS + (size_t)lane*32);
  unsigned k[32];
  #pragma unroll
  for (int c = 0; c < 8; ++c){
    float4 f0 = p4[c*3+0];   // x0 y0 z0 x1
    float4 f1 = p4[c*3+1];   // y1 z1 x2 y2
    float4 f2 = p4[c*3+2];   // z2 x3 y3 z3
    float4 pn = n4[c];
    k[c*4+0] = dkey_xyz(qq,q0,q1,q2, f0.x, f0.y, f0.z, pn.x);
    k[c*4+1] = dkey_xyz(qq,q0,q1,q2, f0.w, f1.x, f1.y, pn.y);
    k[c*4+2] = dkey_xyz(qq,q0,q1,q2, f1.z, f1.w, f2.x, pn.z);
    k[c*4+3] = dkey_xyz(qq,q0,q1,q2, f2.y, f2.z, f2.w, pn.w);
  }
  wave_topk32_u32(k, lane, idx_out + (size_t)bid*KNN);
}

// ---------------- feature norms (frozen: numpy AVX512 pairwise) ----------------
__global__ __launch_bounds__(256) void rownorm_kernel(const float* feat, float* nrm){
  int row = blockIdx.x*256 + threadIdx.x;
  const float* f = feat + (size_t)row*CIN;
  float L[16];
  #pragma unroll
  for (int l = 0; l < 16; ++l){
    float x0 = __fmul_rn(f[l],     f[l]);
    float x1 = __fmul_rn(f[16+l],  f[16+l]);
    float x2 = __fmul_rn(f[32+l],  f[32+l]);
    float x3 = __fmul_rn(f[48+l],  f[48+l]);
    float x4 = __fmul_rn(f[64+l],  f[64+l]);
    float x5 = __fmul_rn(f[80+l],  f[80+l]);
    float x6 = __fmul_rn(f[96+l],  f[96+l]);
    float x7 = __fmul_rn(f[112+l], f[112+l]);
    L[l] = __fadd_rn(
        __fadd_rn(__fadd_rn(x0,x1), __fadd_rn(x2,x3)),
        __fadd_rn(__fadd_rn(x4,x5), __fadd_rn(x6,x7)));
  }
  float T2[4];
  #pragma unroll
  for (int i = 0; i < 4; ++i)
    T2[i] = __fadd_rn(__fadd_rn(L[i], L[i+8]), __fadd_rn(L[i+4], L[i+12]));
  nrm[row] = __fadd_rn(__fadd_rn(T2[0], T2[2]), __fadd_rn(T2[1], T2[3]));
}

// ---------------- feature self-distance: 32x32 tile, 2x2 outputs/thread (rows ty,ty+16 x cols tx,tx+16)
// Per-output FMA chain identical to numpy einsum AVX512 (frozen, bit-exact).
// D is BITWISE symmetric -> compute only tiles mb>=nb; mirror via LDS 32x33 transpose.
__global__ __launch_bounds__(256) void dist_feat_kernel(const float* fb, const float* nrm, float* D){
  __shared__ float Aq[32*PAD];
  __shared__ float Bm[32*PAD];
  int nb = blockIdx.y*32, mb = blockIdx.x*32;
  if (mb < nb) return;              // uniform per block, before any barrier
  int t = threadIdx.x;
  {
    int r = t >> 3, c16 = (t & 7) << 4;
    const float* an = fb + (size_t)(nb + r)*CIN + c16;
    const float* bm = fb + (size_t)(mb + r)*CIN + c16;
    #pragma unroll
    for (int j = 0; j < 4; ++j){
      *(float4*)&Aq[r*PAD + c16 + 4*j] = *(const float4*)&an[4*j];
      *(float4*)&Bm[r*PAD + c16 + 4*j] = *(const float4*)&bm[4*j];
    }
  }
  __syncthreads();
  int tx = t & 15, ty = t >> 4;
  const float* qa0 = &Aq[(ty     )*PAD];
  const float* qa1 = &Aq[(ty + 16)*PAD];
  const float* ma0 = &Bm[(tx     )*PAD];
  const float* ma1 = &Bm[(tx + 16)*PAD];
  float P[2][2][16];
  // chain order over segments: 48,32,16,0,112,96,80,64 (first = mul)
  #pragma unroll
  for (int l = 0; l < 16; ++l){
    float a0 = qa0[48+l], a1 = qa1[48+l], b0 = ma0[48+l], b1 = ma1[48+l];
    P[0][0][l] = __fmul_rn(a0,b0); P[0][1][l] = __fmul_rn(a0,b1);
    P[1][0][l] = __fmul_rn(a1,b0); P[1][1][l] = __fmul_rn(a1,b1);
  }
  const int segs[7] = {32,16,0,112,96,80,64};
  #pragma unroll
  for (int s = 0; s < 7; ++s){
    int off = segs[s];
    #pragma unroll
    for (int l = 0; l < 16; ++l){
      float a0 = qa0[off+l], a1 = qa1[off+l], b0 = ma0[off+l], b1 = ma1[off+l];
      P[0][0][l] = __fmaf_rn(a0,b0,P[0][0][l]); P[0][1][l] = __fmaf_rn(a0,b1,P[0][1][l]);
      P[1][0][l] = __fmaf_rn(a1,b0,P[1][0][l]); P[1][1][l] = __fmaf_rn(a1,b1,P[1][1][l]);
    }
  }
  float val[2][2];
  #pragma unroll
  for (int i = 0; i < 2; ++i){
    int n = nb + ty + 16*i;
    float nn = nrm[n];
    #pragma unroll
    for (int j = 0; j < 2; ++j){
      float T2[4];
      #pragma unroll
      for (int q = 0; q < 4; ++q)
        T2[q] = __fadd_rn(__fadd_rn(P[i][j][q], P[i][j][q+8]), __fadd_rn(P[i][j][q+4], P[i][j][q+12]));
      float dot = __fadd_rn(__fadd_rn(T2[0], T2[2]), __fadd_rn(T2[1], T2[3]));
      int m = mb + tx + 16*j;
      float v = __fsub_rn(__fadd_rn(nn, nrm[m]), __fmul_rn(2.f, dot));
      val[i][j] = v;
      D[(size_t)n*NPTS + m] = v;
    }
  }
  // mirror tile: stage transposed in LDS (reuse Aq after all reads done), write coalesced
  __syncthreads();
  float* Tt = Aq;   // [32][33]
  #pragma unroll
  for (int i = 0; i < 2; ++i)
    #pragma unroll
    for (int j = 0; j < 2; ++j)
      Tt[(tx + 16*j)*33 + (ty + 16*i)] = val[i][j];
  __syncthreads();
  #pragma unroll
  for (int i = 0; i < 2; ++i)
    #pragma unroll
    for (int j = 0; j < 2; ++j)
      D[(size_t)(mb + ty + 16*i)*NPTS + (nb + tx + 16*j)] = Tt[(ty + 16*i)*33 + (tx + 16*j)];
}

// ---------------- feature top-k: float4 loads, m = lane*32 + j (MODE1 contiguous) ----------------
// TWO batches per launch (D0,D1 ping-pong buffers) -> 1024 blocks (2x TLP), 4 launches -> 2.
__global__ __launch_bounds__(256, 6) void topk_row_pair(const float* D0, const float* D1,
                                                        int* idx_out, int batch_base){
  int wave = threadIdx.x >> 6;
  int lane = threadIdx.x & 63;
  int ng = blockIdx.x*4 + wave;          // 0..4095
  int bb = ng >> 11;                     // 0 or 1 (local batch)
  int n  = ng & (NPTS-1);
  const float* D = bb ? D1 : D0;
  const float* src = D + (size_t)n*NPTS + lane*32;
  unsigned k[32];
  #pragma unroll
  for (int i = 0; i < 8; ++i){
    float4 v = *(const float4*)&src[i*4];
    k[i*4+0] = dxf(v.x);
    k[i*4+1] = dxf(v.y);
    k[i*4+2] = dxf(v.z);
    k[i*4+3] = dxf(v.w);
  }
  wave_topk32_u32(k, lane, idx_out + ((size_t)(batch_base + bb)*NPTS + n)*KNN);
}

// ---------------- MFMA GEMM (batched via grid.z): C = bf16(A)[M,K] @ bf16(B^T)[N,K] + bias ----------------
template<typename CT>
__global__ __launch_bounds__(256) void mfma_gemm(const unsigned short* __restrict__ A,
                                                 const unsigned short* __restrict__ Bt,
                                                 const float* __restrict__ bias,
                                                 CT* __restrict__ C, int N, int K,
                                                 size_t sA, size_t sB, size_t sBias, size_t sC){
  int z = blockIdx.z;
  A += (size_t)z*sA; Bt += (size_t)z*sB; bias += (size_t)z*sBias; C += (size_t)z*sC;
  __shared__ unsigned short As[64*40];
  __shared__ unsigned short Bs[64*40];
  int nb = blockIdx.x*64, mb = blockIdx.y*64;
  int t = threadIdx.x;
  int wave = t >> 6, lane = t & 63;
  int m16 = lane & 15, quad = lane >> 4;
  f32x4 acc[4];
  #pragma unroll
  for (int s = 0; s < 4; ++s) acc[s] = (f32x4){0.f, 0.f, 0.f, 0.f};
  int srow = t >> 2, skseg = (t & 3) << 3;
  for (int kt = 0; kt < K; kt += 32){
    __syncthreads();
    *(uint4*)&As[srow*40 + skseg] = *(const uint4*)&A [(size_t)(mb + srow)*K + kt + skseg];
    *(uint4*)&Bs[srow*40 + skseg] = *(const uint4*)&Bt[(size_t)(nb + srow)*K + kt + skseg];
    __syncthreads();
    short8 a = *(const short8*)&As[(wave*16 + m16)*40 + quad*8];
    #pragma unroll
    for (int s = 0; s < 4; ++s){
      short8 b = *(const short8*)&Bs[(s*16 + m16)*40 + quad*8];
      acc[s] = __builtin_amdgcn_mfma_f32_16x16x32_bf16(a, b, acc[s], 0, 0, 0);
    }
  }
  #pragma unroll
  for (int s = 0; s < 4; ++s){
    int col = nb + s*16 + m16;
    float bv = bias[col];
    #pragma unroll
    for (int r = 0; r < 4; ++r){
      int row = mb + wave*16 + quad*4 + r;
      stc(&C[(size_t)row*N + col], acc[s][r] + bv);
    }
  }
}

// ---------------- attention: bf16 X [8192][2048], both branches via grid.y ----------------
// R10 A/B: R7/R9 3-loop structure (max-subtract, exp cache) + SADDR GATHERS ONLY.
// jr[r][k] is wave-uniform (r constant per wave) -> readfirstlane to SGPR; gather becomes
// global_load with scalar base + loop-invariant voffset. FP math untouched -> bit-identical.
// If this regresses vs R9 (~53us), saddr was R8's real problem -> revert permanently.
__global__ __launch_bounds__(256) void attn_kernel(const unsigned short* X,
                                                   const int* idx0, const int* idx1,
                                                   unsigned short* ctx){
  int i = blockIdx.y;
  const int* ip = (i == 0 ? idx0 : idx1);
  int local = threadIdx.x & 127;
  int r     = threadIdx.x >> 7;
  int bn    = blockIdx.x*2 + r;
  int b     = bn >> 11;
  __shared__ int jr[2][KNN];
  if (local < KNN) jr[r][local] = (b << 11) + ip[(size_t)bn*KNN + local];
  __syncthreads();
  const ushort2* X2 = (const ushort2*)X;
  size_t boff = (size_t)i*512 + local;
  ushort2 q2 = X2[(size_t)bn*1024 + boff];
  float qx = bf2f(q2.x), qy = bf2f(q2.y);
  float ex[KNN], ey[KNN];
  float mx = -3.4e38f, my = -3.4e38f;
  #pragma unroll
  for (int k = 0; k < KNN; ++k){
    int row = __builtin_amdgcn_readfirstlane(jr[r][k]);   // wave-uniform -> SGPR base
    const ushort2* kp = X2 + (size_t)row*1024;
    ushort2 k2 = kp[boff + 128];
    ex[k] = (qx - bf2f(k2.x)) * 0.0625f;
    ey[k] = (qy - bf2f(k2.y)) * 0.0625f;
    mx = fmaxf(mx, ex[k]);
    my = fmaxf(my, ey[k]);
  }
  float sx = 0.f, sy = 0.f;
  #pragma unroll
  for (int k = 0; k < KNN; ++k){
    ex[k] = __expf(ex[k] - mx);
    ey[k] = __expf(ey[k] - my);
    sx += ex[k];
    sy += ey[k];
  }
  float ix = 1.f / sx, iy = 1.f / sy;
  float bx = -3.4e38f, by = -3.4e38f;
  #pragma unroll
  for (int k = 0; k < KNN; ++k){
    int row = __builtin_amdgcn_readfirstlane(jr[r][k]);
    const ushort2* vp = X2 + (size_t)row*1024;
    ushort2 v2 = vp[boff + 256];
    float ax = ex[k]*ix - 1.0f;
    float ay = ey[k]*iy - 1.0f;
    bx = fmaxf(bx, ax*bf2f(v2.x));
    by = fmaxf(by, ay*bf2f(v2.y));
  }
  ushort2 o; o.x = f2bf(bx); o.y = f2bf(by);
  ((ushort2*)ctx)[((size_t)i*ROWS + bn)*128 + local] = o;
}

// ---------------- BatchNorm stats (deterministic two-stage, batched over branches) ----------------
__global__ __launch_bounds__(256) void bnx_partial(const unsigned short* X, float* partial){
  int p = blockIdx.x, i = blockIdx.y, c = threadIdx.x;
  const unsigned short* base = X + (size_t)i*1024 + 768 + c;
  float s = 0.f, s2 = 0.f;
  for (int r = 0; r < 256; ++r){
    float v = bf2f(base[(size_t)(p*256 + r)*2048]);
    s += v; s2 += v*v;
  }
  partial[((size_t)i*32 + p)*512 + c]       = s;
  partial[((size_t)i*32 + p)*512 + 256 + c] = s2;
}

__global__ __launch_bounds__(256) void bnf_partial(const unsigned short* F, float* partial){
  int p = blockIdx.x, i = blockIdx.y, c = threadIdx.x;
  const unsigned short* base = F + (size_t)i*ROWS*COUT + c;
  float s = 0.f, s2 = 0.f;
  for (int r = 0; r < 256; ++r){
    float v = bf2f(base[(size_t)(p*256 + r)*COUT]);
    s += v; s2 += v*v;
  }
  partial[((size_t)i*32 + p)*512 + c]       = s;
  partial[((size_t)i*32 + p)*512 + 256 + c] = s2;
}

__global__ __launch_bounds__(256) void bny_partial(const float* Y, float* partial){
  int p = blockIdx.x, c = threadIdx.x;
  float s = 0.f, s2 = 0.f;
  for (int r = 0; r < 256; ++r){
    float v = Y[(size_t)(p*256 + r)*COUT + c];
    s += v; s2 += v*v;
  }
  partial[p*512 + c]       = s;
  partial[p*512 + 256 + c] = s2;
}

__global__ __launch_bounds__(256) void bn_final2(const float* partial, float* stats){
  int i = blockIdx.y, c = threadIdx.x;
  partial += (size_t)i*32*512;
  stats   += (size_t)i*512;
  float s = 0.f, s2 = 0.f;
  for (int p = 0; p < 32; ++p){ s += partial[p*512 + c]; s2 += partial[p*512 + 256 + c]; }
  float mean = s * (1.f/8192.f);
  float var  = s2 * (1.f/8192.f) - mean*mean;   // biased var
  stats[c]       = mean;
  stats[256 + c] = 1.f / sqrtf(var + 1e-5f);
}

// ---------------- m_i = leaky(bn_res(res)) + leaky(bn_ffn(F)) -> Mmat bf16, both branches ----------------
__global__ __launch_bounds__(256) void build_m_kernel(const unsigned short* X, const unsigned short* F,
    const float* stats, const float* gR, const float* bR, const float* gF, const float* bF,
    unsigned short* M){
  int bn = blockIdx.x, c = threadIdx.x;
  #pragma unroll
  for (int i = 0; i < 2; ++i){
    float r  = bf2f(X[(size_t)bn*2048 + i*1024 + 768 + c]);
    float rv = gR[i*COUT+c] * (r - stats[i*512+c]) * stats[i*512+256+c] + bR[i*COUT+c];
    rv = lrelu(rv);
    float f  = bf2f(F[(size_t)i*ROWS*COUT + (size_t)bn*COUT + c]);
    float fv = gF[i*COUT+c] * (f - stats[(2+i)*512+c]) * stats[(2+i)*512+256+c] + bF[i*COUT+c];
    fv = lrelu(fv);
    M[(size_t)bn*512 + i*COUT + c] = f2bf(rv + fv);
  }
}

__global__ __launch_bounds__(256) void final_kernel(const float* Y, const float* stats,
                                                    const float* g, const float* be, float* out){
  int bn = blockIdx.x, c = threadIdx.x;
  float y = Y[(size_t)bn*COUT + c];
  float v = g[c] * (y - stats[c]) * stats[256+c] + be[c];
  out[(size_t)bn*COUT + c] = lrelu(v);
}

extern "C" void kernel_launch(void* const* d_in, const int* in_sizes, int n_in,
                              void* d_out, int out_size, void* d_ws, size_t ws_size,
                              hipStream_t stream){
  const float* xyz      = (const float*)d_in[0];
  const float* base_xyz = (const float*)d_in[1];
  const float* feature  = (const float*)d_in[2];
  const float* qW = (const float*)d_in[3];
  const float* qb = (const float*)d_in[4];
  const float* kW = (const float*)d_in[5];
  const float* kb = (const float*)d_in[6];
  const float* vW = (const float*)d_in[7];
  const float* vb = (const float*)d_in[8];
  const float* rW = (const float*)d_in[9];
  const float* rb = (const float*)d_in[10];
  const float* res_gamma = (const float*)d_in[11];
  const float* res_beta  = (const float*)d_in[12];
  const float* ffnW = (const float*)d_in[13];
  const float* ffnb = (const float*)d_in[14];
  const float* ffn_gamma = (const float*)d_in[15];
  const float* ffn_beta  = (const float*)d_in[16];
  const float* fcW = (const float*)d_in[17];
  const float* fcb = (const float*)d_in[18];
  const float* fc_gamma = (const float*)d_in[19];
  const float* fc_beta  = (const float*)d_in[20];
  float* out = (float*)d_out;

  // ---- workspace plan (~62 MB, region reuse) ----
  char* ws = (char*)d_ws;
  size_t o = 0;
  auto alloc = [&](size_t bytes)->char*{
    char* p = ws + o;
    o += (bytes + 255) & ~(size_t)255;
    return p;
  };
  int*            idx0    = (int*)           alloc((size_t)ROWS*KNN*4);
  int*            idx1    = (int*)           alloc((size_t)ROWS*KNN*4);
  float*          nrm     = (float*)         alloc((size_t)ROWS*4);
  float*          ppxyz   = (float*)         alloc((size_t)N_PP*4);
  float*          bcat    = (float*)         alloc((size_t)2048*4);
  unsigned short* WT_x    = (unsigned short*)alloc((size_t)2048*CIN*2);
  unsigned short* WT_ffn  = (unsigned short*)alloc((size_t)2*COUT*COUT*2);
  unsigned short* WT_fc   = (unsigned short*)alloc((size_t)COUT*512*2);
  unsigned short* feat_bf = (unsigned short*)alloc((size_t)ROWS*CIN*2);
  float*          stats   = (float*)         alloc((size_t)5*512*4);
  float*          partial = (float*)         alloc((size_t)4*32*512*4);   // 4 slots (bnx 0-1, bnf 2-3)
  char*           R1      = alloc((size_t)ROWS*2048*2);   // 32 MB: D0+D1 fp32 (2x16MB) -> X bf16 [8192][2048]
  char*           R2      = alloc((size_t)ROWS*COUT*4);   //  8 MB: ctx_bf -> Y fp32
  unsigned short* Mmat_bf = (unsigned short*)alloc((size_t)ROWS*512*2);   // 8 MB
  unsigned short* F_bf    = (unsigned short*)alloc((size_t)2*ROWS*COUT*2);// 8 MB
  float*          D0   = (float*)R1;                       // 16 MB
  float*          D1   = (float*)(R1 + (size_t)NPTS*NPTS*4); // second 16 MB (dead until X_bf)
  unsigned short* X_bf = (unsigned short*)R1;
  unsigned short* ctx_bf = (unsigned short*)R2;
  float*          Y    = (float*)R2;

  // one-time prep (fused)
  pack_all<<<(N_WTX+N_WFFN+N_WFC+N_FEAT+N_PP)/256, 256, 0, stream>>>(
      qW,kW,vW,rW,qb,kb,vb,rb, ffnW, fcW, feature, base_xyz,
      WT_x, bcat, WT_ffn, WT_fc, feat_bf, ppxyz);

  knn_xyz_kernel<<<ROWS/4, 256, 0, stream>>>(xyz, base_xyz, ppxyz, idx0);
  rownorm_kernel<<<ROWS/256, 256, 0, stream>>>(feature, nrm);

  // per-batch feature-distance (frozen bit-exact, symmetry-halved) + paired top-k
  for (int pair = 0; pair < 2; ++pair){
    int b0 = pair*2, b1 = pair*2 + 1;
    dist_feat_kernel<<<dim3(NPTS/32, NPTS/32), 256, 0, stream>>>(
        feature + (size_t)b0*NPTS*CIN, nrm + (size_t)b0*NPTS, D0);
    dist_feat_kernel<<<dim3(NPTS/32, NPTS/32), 256, 0, stream>>>(
        feature + (size_t)b1*NPTS*CIN, nrm + (size_t)b1*NPTS, D1);
    topk_row_pair<<<(2*NPTS)/4, 256, 0, stream>>>(D0, D1, idx1, b0);
  }

  // X[8192][2048] bf16 = feat_bf @ WT_x^T, both branches in one launch
  mfma_gemm<unsigned short><<<dim3(2048/64, ROWS/64, 1), 256, 0, stream>>>(
      feat_bf, WT_x, bcat, X_bf, 2048, CIN, 0, 0, 0, 0);

  // attention: both branches, one launch
  attn_kernel<<<dim3(ROWS/2, 2), 256, 0, stream>>>(X_bf, idx0, idx1, ctx_bf);

  // res BN partials (slots 0,1)
  bnx_partial<<<dim3(32, 2), 256, 0, stream>>>(X_bf, partial);

  // ffn GEMM: F_bf[i] = ctx_bf[i] @ ffnW_i + ffnb_i  (batched grid.z=2)
  mfma_gemm<unsigned short><<<dim3(COUT/64, ROWS/64, 2), 256, 0, stream>>>(
      ctx_bf, WT_ffn, ffnb, F_bf, COUT, COUT,
      (size_t)ROWS*COUT, (size_t)COUT*COUT, COUT, (size_t)ROWS*COUT);

  // ffn BN partials (slots 2,3) then ONE final for slots 0-3
  bnf_partial<<<dim3(32, 2), 256, 0, stream>>>(F_bf, partial + (size_t)2*32*512);
  bn_final2<<<dim3(1, 4), 256, 0, stream>>>(partial, stats);          // slots 0..3

  build_m_kernel<<<ROWS, 256, 0, stream>>>(X_bf, F_bf, stats,
      res_gamma, res_beta, ffn_gamma, ffn_beta, Mmat_bf);

  // fc: Y = Mmat @ fcW + fcb  (ctx region dead -> Y)
  mfma_gemm<float><<<dim3(COUT/64, ROWS/64, 1), 256, 0, stream>>>(
      Mmat_bf, WT_fc, fcb, Y, COUT, 512, 0, 0, 0, 0);

  bny_partial<<<32, 256, 0, stream>>>(Y, partial);
  bn_final2<<<dim3(1, 1), 256, 0, stream>>>(partial, stats + 4*512);  // slot 4

  final_kernel<<<ROWS, 256, 0, stream>>>(Y, stats + 4*512, fc_gamma, fc_beta, out);
}

// Round 11
// 396.363 us; speedup vs baseline: 1.1092x; 1.1092x over previous
//
#include <hip/hip_runtime.h>
#include <hip/hip_bf16.h>

typedef __hip_bfloat16 bf16;
typedef __attribute__((ext_vector_type(8))) short short8;
typedef __attribute__((ext_vector_type(4))) float f32x4;

#define ROWS 8192   // B*N
#define NPTS 2048
#define CIN  128
#define COUT 256
#define KNN  32
#define PAD  132    // dist_feat LDS leading dim: 16B-aligned rows -> ds_read_b128 (PAD=129 regressed, R13)

__device__ inline float lrelu(float x){ return x >= 0.f ? x : 0.2f*x; }
__device__ inline unsigned short f2bf(float x){
  bf16 h = __float2bfloat16(x);
  return *(unsigned short*)&h;
}
__device__ inline float bf2f(unsigned short u){ return __uint_as_float((unsigned)u << 16); }
__device__ inline void stc(float* p, float v){ *p = v; }
__device__ inline void stc(unsigned short* p, float v){ *p = f2bf(v); }

// ---------------- fused one-time prep: WT_x, bcat, WT_ffn, WT_fc, feat_bf, pp(base_xyz), rownorm ----------------
#define N_WTX   (2048*CIN)          // 262144
#define N_WFFN  (2*COUT*COUT)       // 131072
#define N_WFC   (COUT*512)          // 131072
#define N_FEAT  (ROWS*CIN)          // 1048576
#define N_PP    8192                // 4 batches x 2048 base-point norms
#define N_NRM   8192                // feature row norms (one thread per row, frozen chain)
__global__ __launch_bounds__(256) void pack_all(
    const float* qW, const float* kW, const float* vW, const float* rW,
    const float* qb, const float* kb, const float* vb, const float* rb,
    const float* ffnW, const float* fcW, const float* feature, const float* base_xyz,
    unsigned short* WT_x, float* bcat, unsigned short* WT_ffn,
    unsigned short* WT_fc, unsigned short* feat_bf, float* ppxyz, float* nrm){
  int t = blockIdx.x*256 + threadIdx.x;
  if (t < N_WTX){
    int c = t >> 7, r = t & 127;
    int g = c >> 8, i = g >> 2, tt = g & 3, cc = c & 255;
    const float* W = (tt==0?qW: tt==1?kW: tt==2?vW: rW) + (size_t)i*CIN*COUT;
    WT_x[t] = f2bf(W[r*COUT + cc]);
    if (r == 0){
      const float* bb = (tt==0?qb: tt==1?kb: tt==2?vb: rb) + i*COUT;
      bcat[c] = bb[cc];
    }
  } else if (t < N_WTX + N_WFFN){
    int u = t - N_WTX;
    int i = u >> 16, n = (u >> 8) & 255, k = u & 255;
    WT_ffn[u] = f2bf(ffnW[(size_t)i*65536 + k*256 + n]);
  } else if (t < N_WTX + N_WFFN + N_WFC){
    int u = t - N_WTX - N_WFFN;
    int n = u >> 9, k = u & 511;
    WT_fc[u] = f2bf(fcW[(size_t)k*256 + n]);
  } else if (t < N_WTX + N_WFFN + N_WFC + N_FEAT){
    int u = t - N_WTX - N_WFFN - N_WFC;
    feat_bf[u] = f2bf(feature[u]);
  } else if (t < N_WTX + N_WFFN + N_WFC + N_FEAT + N_PP){
    // base-point norms, frozen chain
    int u = t - N_WTX - N_WFFN - N_WFC - N_FEAT;
    float p0 = base_xyz[(size_t)u*3+0];
    float p1 = base_xyz[(size_t)u*3+1];
    float p2 = base_xyz[(size_t)u*3+2];
    ppxyz[u] = __fadd_rn(__fadd_rn(__fmul_rn(p0,p0), __fmul_rn(p1,p1)), __fmul_rn(p2,p2));
  } else {
    // feature row norms (frozen: numpy AVX512 pairwise) -- was rownorm_kernel
    int row = t - N_WTX - N_WFFN - N_WFC - N_FEAT - N_PP;   // exactly N_NRM
    const float* f = feature + (size_t)row*CIN;
    float L[16];
    #pragma unroll
    for (int l = 0; l < 16; ++l){
      float x0 = __fmul_rn(f[l],     f[l]);
      float x1 = __fmul_rn(f[16+l],  f[16+l]);
      float x2 = __fmul_rn(f[32+l],  f[32+l]);
      float x3 = __fmul_rn(f[48+l],  f[48+l]);
      float x4 = __fmul_rn(f[64+l],  f[64+l]);
      float x5 = __fmul_rn(f[80+l],  f[80+l]);
      float x6 = __fmul_rn(f[96+l],  f[96+l]);
      float x7 = __fmul_rn(f[112+l], f[112+l]);
      L[l] = __fadd_rn(
          __fadd_rn(__fadd_rn(x0,x1), __fadd_rn(x2,x3)),
          __fadd_rn(__fadd_rn(x4,x5), __fadd_rn(x6,x7)));
    }
    float T2[4];
    #pragma unroll
    for (int i = 0; i < 4; ++i)
      T2[i] = __fadd_rn(__fadd_rn(L[i], L[i+8]), __fadd_rn(L[i+4], L[i+12]));
    nrm[row] = __fadd_rn(__fadd_rn(T2[0], T2[2]), __fadd_rn(T2[1], T2[3]));
  }
}

// ---------------- wave-parallel top-32, 32-bit keys, MODE1 ownership ----------------
// m = lane*32 + slot (lane owns 32 CONTIGUOUS indices, keys in registers).
// Key = monotone u32 transform of fp32 distance. Exact numpy tie-order (lowest m among
// equal dists) decomposes: ballot lowest LANE with min ✓ then owner's lowest SLOT ✓.
// Reduce = 4x v_min_u32+row_shr DPP (row_bcast is REMOVED on CDNA2+), 4x readlane +
// scalar min, ballot+ctz for owner. Sentinel 0xFFFFFFFF unreachable for finite inputs.
__device__ inline unsigned dxf(float d){
  unsigned u = __float_as_uint(d);
  return (u & 0x80000000u) ? ~u : (u | 0x80000000u);
}
__device__ inline unsigned umin32(unsigned a, unsigned b){ return a < b ? a : b; }

#define DPP_ROW_SHR1    0x111
#define DPP_ROW_SHR2    0x112
#define DPP_ROW_SHR4    0x114
#define DPP_ROW_SHR8    0x118

template<int CTRL>
__device__ inline unsigned dpp_umin_step(unsigned v){
  // bound_ctrl=false, old=own value: invalid lanes keep own -> min(v,v)=v
  unsigned s = (unsigned)__builtin_amdgcn_update_dpp((int)v, (int)v, CTRL, 0xF, 0xF, false);
  return s < v ? s : v;
}

#define TOPK32_CASE(G)                                                   \
  {                                                                      \
    int jw = 7;                                                          \
    _Pragma("unroll")                                                    \
    for (int j = 7; j >= 0; --j) if (k[G*8+j] == minv) jw = j;           \
    slot = G*8 + jw;                                                     \
    _Pragma("unroll")                                                    \
    for (int j = 0; j < 8; ++j) if (j == jw) k[G*8+j] = ~0u;             \
    unsigned nm = k[G*8];                                                \
    _Pragma("unroll")                                                    \
    for (int j = 1; j < 8; ++j) nm = umin32(nm, k[G*8+j]);               \
    g[G] = nm;                                                           \
  }

__device__ inline void wave_topk32_u32(unsigned* k, int lane, int* out){
  unsigned g[4];
  #pragma unroll
  for (int gi = 0; gi < 4; ++gi){
    unsigned m = k[gi*8];
    #pragma unroll
    for (int j = 1; j < 8; ++j) m = umin32(m, k[gi*8+j]);
    g[gi] = m;
  }
  unsigned outv = 0;
  for (int r = 0; r < KNN; ++r){
    unsigned lm = umin32(umin32(g[0], g[1]), umin32(g[2], g[3]));  // lane's own min
    unsigned m = lm;
    m = dpp_umin_step<DPP_ROW_SHR1>(m);
    m = dpp_umin_step<DPP_ROW_SHR2>(m);
    m = dpp_umin_step<DPP_ROW_SHR4>(m);
    m = dpp_umin_step<DPP_ROW_SHR8>(m);
    unsigned b0 = (unsigned)__builtin_amdgcn_readlane((int)m, 15);
    unsigned b1 = (unsigned)__builtin_amdgcn_readlane((int)m, 31);
    unsigned b2 = (unsigned)__builtin_amdgcn_readlane((int)m, 47);
    unsigned b3 = (unsigned)__builtin_amdgcn_readlane((int)m, 63);
    unsigned minv = umin32(umin32(b0, b1), umin32(b2, b3));        // wave-uniform
    unsigned long long ball = __ballot(lm == minv);
    int owner = (int)__builtin_ctzll(ball);                        // lowest tied lane = lowest m
    int slot = 0;
    if (owner == lane){
      int gw = (g[0]==minv) ? 0 : (g[1]==minv) ? 1 : (g[2]==minv) ? 2 : 3;  // lowest group
      if      (gw == 0) TOPK32_CASE(0)
      else if (gw == 1) TOPK32_CASE(1)
      else if (gw == 2) TOPK32_CASE(2)
      else              TOPK32_CASE(3)
    }
    int slotw = __builtin_amdgcn_readlane(slot, owner);            // wave-uniform
    unsigned wm = (unsigned)(owner*32 + slotw);
    outv = (lane == r) ? wm : outv;                                // lane r captures winner r
  }
  if (lane < KNN) out[lane] = (int)outv;
}

// ---------------- xyz KNN (frozen: numpy-faithful fp32, bit-exact) ----------------
// LDS-free, register-resident 32-bit keys; lane owns 32 contiguous points.
// pp loaded from precomputed table (pack_all, identical FP chain -> identical bits).
__device__ inline unsigned dkey_xyz(float qq, float q0, float q1, float q2,
                                    float p0, float p1, float p2, float pp){
  float dot = __fmul_rn(q0,p0);
  dot = __fadd_rn(dot, __fmul_rn(q1,p1));
  dot = __fadd_rn(dot, __fmul_rn(q2,p2));
  float d = __fsub_rn(__fadd_rn(qq, pp), __fmul_rn(2.f, dot));
  return dxf(d);
}

__global__ __launch_bounds__(256, 6) void knn_xyz_kernel(const float* xyz, const float* base,
                                                         const float* ppxyz, int* idx_out){
  int wave = threadIdx.x >> 6;
  int lane = threadIdx.x & 63;
  int bid = blockIdx.x*4 + wave;
  int b = bid >> 11;
  float q0 = xyz[(size_t)bid*3+0];
  float q1 = xyz[(size_t)bid*3+1];
  float q2 = xyz[(size_t)bid*3+2];
  float qq = __fadd_rn(__fadd_rn(__fmul_rn(q0,q0), __fmul_rn(q1,q1)), __fmul_rn(q2,q2));
  // lane's 32 points: m = lane*32 + (c*4 + j); 96 floats = 24 float4 per lane, 16B-aligned
  const float4* p4 = (const float4*)(base + (size_t)b*NPTS*3 + (size_t)lane*96);
  const float4* n4 = (const float4*)(ppxyz + (size_t)b*NPTS + (size_t)lane*32);
  unsigned k[32];
  #pragma unroll
  for (int c = 0; c < 8; ++c){
    float4 f0 = p4[c*3+0];   // x0 y0 z0 x1
    float4 f1 = p4[c*3+1];   // y1 z1 x2 y2
    float4 f2 = p4[c*3+2];   // z2 x3 y3 z3
    float4 pn = n4[c];
    k[c*4+0] = dkey_xyz(qq,q0,q1,q2, f0.x, f0.y, f0.z, pn.x);
    k[c*4+1] = dkey_xyz(qq,q0,q1,q2, f0.w, f1.x, f1.y, pn.y);
    k[c*4+2] = dkey_xyz(qq,q0,q1,q2, f1.z, f1.w, f2.x, pn.z);
    k[c*4+3] = dkey_xyz(qq,q0,q1,q2, f2.y, f2.z, f2.w, pn.w);
  }
  wave_topk32_u32(k, lane, idx_out + (size_t)bid*KNN);
}

// ---------------- feature self-distance: 32x32 tile, 2x2 outputs/thread (rows ty,ty+16 x cols tx,tx+16)
// Per-output FMA chain identical to numpy einsum AVX512 (frozen, bit-exact).
// D is BITWISE symmetric -> triangular grid (2080 tiles/batch, no empty blocks);
// mirror tile via LDS 32x33 transpose. R11: grid.z = batch within pair (D0/D1).
__global__ __launch_bounds__(256) void dist_feat_kernel(const float* feature, const float* nrm4,
                                                        float* D0, float* D1, int pair){
  __shared__ float Aq[32*PAD];
  __shared__ float Bm[32*PAD];
  int z = blockIdx.z;
  const float* fb  = feature + (size_t)(pair*2 + z)*NPTS*CIN;
  const float* nrm = nrm4    + (size_t)(pair*2 + z)*NPTS;
  float* D = z ? D1 : D0;
  // triangular decode: t = v*(v+1)/2 + u, u <= v  (nb = u*32 <= mb = v*32)
  int t0 = blockIdx.x;
  int v = (int)((__fsqrt_rn(8.f*(float)t0 + 1.f) - 1.f)*0.5f);
  while ((v+1)*(v+2)/2 <= t0) ++v;
  while (v*(v+1)/2 > t0) --v;
  int u = t0 - v*(v+1)/2;
  int nb = u*32, mb = v*32;
  int t = threadIdx.x;
  {
    int r = t >> 3, c16 = (t & 7) << 4;
    const float* an = fb + (size_t)(nb + r)*CIN + c16;
    const float* bm = fb + (size_t)(mb + r)*CIN + c16;
    #pragma unroll
    for (int j = 0; j < 4; ++j){
      *(float4*)&Aq[r*PAD + c16 + 4*j] = *(const float4*)&an[4*j];
      *(float4*)&Bm[r*PAD + c16 + 4*j] = *(const float4*)&bm[4*j];
    }
  }
  __syncthreads();
  int tx = t & 15, ty = t >> 4;
  const float* qa0 = &Aq[(ty     )*PAD];
  const float* qa1 = &Aq[(ty + 16)*PAD];
  const float* ma0 = &Bm[(tx     )*PAD];
  const float* ma1 = &Bm[(tx + 16)*PAD];
  float P[2][2][16];
  // chain order over segments: 48,32,16,0,112,96,80,64 (first = mul)
  #pragma unroll
  for (int l = 0; l < 16; ++l){
    float a0 = qa0[48+l], a1 = qa1[48+l], b0 = ma0[48+l], b1 = ma1[48+l];
    P[0][0][l] = __fmul_rn(a0,b0); P[0][1][l] = __fmul_rn(a0,b1);
    P[1][0][l] = __fmul_rn(a1,b0); P[1][1][l] = __fmul_rn(a1,b1);
  }
  const int segs[7] = {32,16,0,112,96,80,64};
  #pragma unroll
  for (int s = 0; s < 7; ++s){
    int off = segs[s];
    #pragma unroll
    for (int l = 0; l < 16; ++l){
      float a0 = qa0[off+l], a1 = qa1[off+l], b0 = ma0[off+l], b1 = ma1[off+l];
      P[0][0][l] = __fmaf_rn(a0,b0,P[0][0][l]); P[0][1][l] = __fmaf_rn(a0,b1,P[0][1][l]);
      P[1][0][l] = __fmaf_rn(a1,b0,P[1][0][l]); P[1][1][l] = __fmaf_rn(a1,b1,P[1][1][l]);
    }
  }
  float val[2][2];
  #pragma unroll
  for (int i = 0; i < 2; ++i){
    int n = nb + ty + 16*i;
    float nn = nrm[n];
    #pragma unroll
    for (int j = 0; j < 2; ++j){
      float T2[4];
      #pragma unroll
      for (int q = 0; q < 4; ++q)
        T2[q] = __fadd_rn(__fadd_rn(P[i][j][q], P[i][j][q+8]), __fadd_rn(P[i][j][q+4], P[i][j][q+12]));
      float dot = __fadd_rn(__fadd_rn(T2[0], T2[2]), __fadd_rn(T2[1], T2[3]));
      int m = mb + tx + 16*j;
      float vv = __fsub_rn(__fadd_rn(nn, nrm[m]), __fmul_rn(2.f, dot));
      val[i][j] = vv;
      D[(size_t)n*NPTS + m] = vv;
    }
  }
  // mirror tile: stage transposed in LDS (reuse Aq after all reads done), write coalesced
  __syncthreads();
  float* Tt = Aq;   // [32][33]
  #pragma unroll
  for (int i = 0; i < 2; ++i)
    #pragma unroll
    for (int j = 0; j < 2; ++j)
      Tt[(tx + 16*j)*33 + (ty + 16*i)] = val[i][j];
  __syncthreads();
  #pragma unroll
  for (int i = 0; i < 2; ++i)
    #pragma unroll
    for (int j = 0; j < 2; ++j)
      D[(size_t)(mb + ty + 16*i)*NPTS + (nb + tx + 16*j)] = Tt[(ty + 16*i)*33 + (tx + 16*j)];
}

// ---------------- feature top-k: float4 loads, m = lane*32 + j (MODE1 contiguous) ----------------
// TWO batches per launch (D0,D1 ping-pong buffers) -> 1024 blocks (2x TLP), 4 launches -> 2.
__global__ __launch_bounds__(256, 6) void topk_row_pair(const float* D0, const float* D1,
                                                        int* idx_out, int batch_base){
  int wave = threadIdx.x >> 6;
  int lane = threadIdx.x & 63;
  int ng = blockIdx.x*4 + wave;          // 0..4095
  int bb = ng >> 11;                     // 0 or 1 (local batch)
  int n  = ng & (NPTS-1);
  const float* D = bb ? D1 : D0;
  const float* src = D + (size_t)n*NPTS + lane*32;
  unsigned k[32];
  #pragma unroll
  for (int i = 0; i < 8; ++i){
    float4 v = *(const float4*)&src[i*4];
    k[i*4+0] = dxf(v.x);
    k[i*4+1] = dxf(v.y);
    k[i*4+2] = dxf(v.z);
    k[i*4+3] = dxf(v.w);
  }
  wave_topk32_u32(k, lane, idx_out + ((size_t)(batch_base + bb)*NPTS + n)*KNN);
}

// ---------------- MFMA GEMM (batched via grid.z): C = bf16(A)[M,K] @ bf16(B^T)[N,K] + bias ----------------
template<typename CT>
__global__ __launch_bounds__(256) void mfma_gemm(const unsigned short* __restrict__ A,
                                                 const unsigned short* __restrict__ Bt,
                                                 const float* __restrict__ bias,
                                                 CT* __restrict__ C, int N, int K,
                                                 size_t sA, size_t sB, size_t sBias, size_t sC){
  int z = blockIdx.z;
  A += (size_t)z*sA; Bt += (size_t)z*sB; bias += (size_t)z*sBias; C += (size_t)z*sC;
  __shared__ unsigned short As[64*40];
  __shared__ unsigned short Bs[64*40];
  int nb = blockIdx.x*64, mb = blockIdx.y*64;
  int t = threadIdx.x;
  int wave = t >> 6, lane = t & 63;
  int m16 = lane & 15, quad = lane >> 4;
  f32x4 acc[4];
  #pragma unroll
  for (int s = 0; s < 4; ++s) acc[s] = (f32x4){0.f, 0.f, 0.f, 0.f};
  int srow = t >> 2, skseg = (t & 3) << 3;
  for (int kt = 0; kt < K; kt += 32){
    __syncthreads();
    *(uint4*)&As[srow*40 + skseg] = *(const uint4*)&A [(size_t)(mb + srow)*K + kt + skseg];
    *(uint4*)&Bs[srow*40 + skseg] = *(const uint4*)&Bt[(size_t)(nb + srow)*K + kt + skseg];
    __syncthreads();
    short8 a = *(const short8*)&As[(wave*16 + m16)*40 + quad*8];
    #pragma unroll
    for (int s = 0; s < 4; ++s){
      short8 b = *(const short8*)&Bs[(s*16 + m16)*40 + quad*8];
      acc[s] = __builtin_amdgcn_mfma_f32_16x16x32_bf16(a, b, acc[s], 0, 0, 0);
    }
  }
  #pragma unroll
  for (int s = 0; s < 4; ++s){
    int col = nb + s*16 + m16;
    float bv = bias[col];
    #pragma unroll
    for (int r = 0; r < 4; ++r){
      int row = mb + wave*16 + quad*4 + r;
      stc(&C[(size_t)row*N + col], acc[s][r] + bv);
    }
  }
}

// ---------------- attention: bf16 X [8192][2048], both branches via grid.y; ushort2 gathers ----------------
// R11: exact R9 structure (3 loops, max-subtract, exp cache, VGPR-addressed gathers).
// A/B history: R8 merged-loop regressed (latency-bound chain); R10 saddr-only regressed
// (readfirstlane serialization, 56.7us vs 53). This shape is the validated optimum ~53us @90% VALU.
__global__ __launch_bounds__(256) void attn_kernel(const unsigned short* X,
                                                   const int* idx0, const int* idx1,
                                                   unsigned short* ctx){
  int i = blockIdx.y;
  const int* ip = (i == 0 ? idx0 : idx1);
  int local = threadIdx.x & 127;
  int r     = threadIdx.x >> 7;
  int bn    = blockIdx.x*2 + r;
  int b     = bn >> 11;
  __shared__ int jr[2][KNN];
  if (local < KNN) jr[r][local] = (b << 11) + ip[(size_t)bn*KNN + local];
  __syncthreads();
  const ushort2* X2 = (const ushort2*)X;
  size_t boff = (size_t)i*512 + local;
  ushort2 q2 = X2[(size_t)bn*1024 + boff];
  float qx = bf2f(q2.x), qy = bf2f(q2.y);
  float ex[KNN], ey[KNN];
  float mx = -3.4e38f, my = -3.4e38f;
  #pragma unroll
  for (int k = 0; k < KNN; ++k){
    ushort2 k2 = X2[(size_t)jr[r][k]*1024 + boff + 128];
    ex[k] = (qx - bf2f(k2.x)) * 0.0625f;
    ey[k] = (qy - bf2f(k2.y)) * 0.0625f;
    mx = fmaxf(mx, ex[k]);
    my = fmaxf(my, ey[k]);
  }
  float sx = 0.f, sy = 0.f;
  #pragma unroll
  for (int k = 0; k < KNN; ++k){
    ex[k] = __expf(ex[k] - mx);
    ey[k] = __expf(ey[k] - my);
    sx += ex[k];
    sy += ey[k];
  }
  float ix = 1.f / sx, iy = 1.f / sy;
  float bx = -3.4e38f, by = -3.4e38f;
  #pragma unroll
  for (int k = 0; k < KNN; ++k){
    ushort2 v2 = X2[(size_t)jr[r][k]*1024 + boff + 256];
    float ax = ex[k]*ix - 1.0f;
    float ay = ey[k]*iy - 1.0f;
    bx = fmaxf(bx, ax*bf2f(v2.x));
    by = fmaxf(by, ay*bf2f(v2.y));
  }
  ushort2 o; o.x = f2bf(bx); o.y = f2bf(by);
  ((ushort2*)ctx)[((size_t)i*ROWS + bn)*128 + local] = o;
}

// ---------------- BatchNorm stats (deterministic two-stage, batched over branches) ----------------
__global__ __launch_bounds__(256) void bnx_partial(const unsigned short* X, float* partial){
  int p = blockIdx.x, i = blockIdx.y, c = threadIdx.x;
  const unsigned short* base = X + (size_t)i*1024 + 768 + c;
  float s = 0.f, s2 = 0.f;
  for (int r = 0; r < 256; ++r){
    float v = bf2f(base[(size_t)(p*256 + r)*2048]);
    s += v; s2 += v*v;
  }
  partial[((size_t)i*32 + p)*512 + c]       = s;
  partial[((size_t)i*32 + p)*512 + 256 + c] = s2;
}

__global__ __launch_bounds__(256) void bnf_partial(const unsigned short* F, float* partial){
  int p = blockIdx.x, i = blockIdx.y, c = threadIdx.x;
  const unsigned short* base = F + (size_t)i*ROWS*COUT + c;
  float s = 0.f, s2 = 0.f;
  for (int r = 0; r < 256; ++r){
    float v = bf2f(base[(size_t)(p*256 + r)*COUT]);
    s += v; s2 += v*v;
  }
  partial[((size_t)i*32 + p)*512 + c]       = s;
  partial[((size_t)i*32 + p)*512 + 256 + c] = s2;
}

__global__ __launch_bounds__(256) void bny_partial(const float* Y, float* partial){
  int p = blockIdx.x, c = threadIdx.x;
  float s = 0.f, s2 = 0.f;
  for (int r = 0; r < 256; ++r){
    float v = Y[(size_t)(p*256 + r)*COUT + c];
    s += v; s2 += v*v;
  }
  partial[p*512 + c]       = s;
  partial[p*512 + 256 + c] = s2;
}

__global__ __launch_bounds__(256) void bn_final2(const float* partial, float* stats){
  int i = blockIdx.y, c = threadIdx.x;
  partial += (size_t)i*32*512;
  stats   += (size_t)i*512;
  float s = 0.f, s2 = 0.f;
  for (int p = 0; p < 32; ++p){ s += partial[p*512 + c]; s2 += partial[p*512 + 256 + c]; }
  float mean = s * (1.f/8192.f);
  float var  = s2 * (1.f/8192.f) - mean*mean;   // biased var
  stats[c]       = mean;
  stats[256 + c] = 1.f / sqrtf(var + 1e-5f);
}

// ---------------- m_i = leaky(bn_res(res)) + leaky(bn_ffn(F)) -> Mmat bf16, both branches ----------------
__global__ __launch_bounds__(256) void build_m_kernel(const unsigned short* X, const unsigned short* F,
    const float* stats, const float* gR, const float* bR, const float* gF, const float* bF,
    unsigned short* M){
  int bn = blockIdx.x, c = threadIdx.x;
  #pragma unroll
  for (int i = 0; i < 2; ++i){
    float r  = bf2f(X[(size_t)bn*2048 + i*1024 + 768 + c]);
    float rv = gR[i*COUT+c] * (r - stats[i*512+c]) * stats[i*512+256+c] + bR[i*COUT+c];
    rv = lrelu(rv);
    float f  = bf2f(F[(size_t)i*ROWS*COUT + (size_t)bn*COUT + c]);
    float fv = gF[i*COUT+c] * (f - stats[(2+i)*512+c]) * stats[(2+i)*512+256+c] + bF[i*COUT+c];
    fv = lrelu(fv);
    M[(size_t)bn*512 + i*COUT + c] = f2bf(rv + fv);
  }
}

__global__ __launch_bounds__(256) void final_kernel(const float* Y, const float* stats,
                                                    const float* g, const float* be, float* out){
  int bn = blockIdx.x, c = threadIdx.x;
  float y = Y[(size_t)bn*COUT + c];
  float v = g[c] * (y - stats[c]) * stats[256+c] + be[c];
  out[(size_t)bn*COUT + c] = lrelu(v);
}

extern "C" void kernel_launch(void* const* d_in, const int* in_sizes, int n_in,
                              void* d_out, int out_size, void* d_ws, size_t ws_size,
                              hipStream_t stream){
  const float* xyz      = (const float*)d_in[0];
  const float* base_xyz = (const float*)d_in[1];
  const float* feature  = (const float*)d_in[2];
  const float* qW = (const float*)d_in[3];
  const float* qb = (const float*)d_in[4];
  const float* kW = (const float*)d_in[5];
  const float* kb = (const float*)d_in[6];
  const float* vW = (const float*)d_in[7];
  const float* vb = (const float*)d_in[8];
  const float* rW = (const float*)d_in[9];
  const float* rb = (const float*)d_in[10];
  const float* res_gamma = (const float*)d_in[11];
  const float* res_beta  = (const float*)d_in[12];
  const float* ffnW = (const float*)d_in[13];
  const float* ffnb = (const float*)d_in[14];
  const float* ffn_gamma = (const float*)d_in[15];
  const float* ffn_beta  = (const float*)d_in[16];
  const float* fcW = (const float*)d_in[17];
  const float* fcb = (const float*)d_in[18];
  const float* fc_gamma = (const float*)d_in[19];
  const float* fc_beta  = (const float*)d_in[20];
  float* out = (float*)d_out;

  // ---- workspace plan (~62 MB, region reuse) ----
  char* ws = (char*)d_ws;
  size_t o = 0;
  auto alloc = [&](size_t bytes)->char*{
    char* p = ws + o;
    o += (bytes + 255) & ~(size_t)255;
    return p;
  };
  int*            idx0    = (int*)           alloc((size_t)ROWS*KNN*4);
  int*            idx1    = (int*)           alloc((size_t)ROWS*KNN*4);
  float*          nrm     = (float*)         alloc((size_t)ROWS*4);
  float*          ppxyz   = (float*)         alloc((size_t)N_PP*4);
  float*          bcat    = (float*)         alloc((size_t)2048*4);
  unsigned short* WT_x    = (unsigned short*)alloc((size_t)2048*CIN*2);
  unsigned short* WT_ffn  = (unsigned short*)alloc((size_t)2*COUT*COUT*2);
  unsigned short* WT_fc   = (unsigned short*)alloc((size_t)COUT*512*2);
  unsigned short* feat_bf = (unsigned short*)alloc((size_t)ROWS*CIN*2);
  float*          stats   = (float*)         alloc((size_t)5*512*4);
  float*          partial = (float*)         alloc((size_t)4*32*512*4);   // 4 slots (bnx 0-1, bnf 2-3)
  char*           R1      = alloc((size_t)ROWS*2048*2);   // 32 MB: D0+D1 fp32 (2x16MB) -> X bf16 [8192][2048]
  char*           R2      = alloc((size_t)ROWS*COUT*4);   //  8 MB: ctx_bf -> Y fp32
  unsigned short* Mmat_bf = (unsigned short*)alloc((size_t)ROWS*512*2);   // 8 MB
  unsigned short* F_bf    = (unsigned short*)alloc((size_t)2*ROWS*COUT*2);// 8 MB
  float*          D0   = (float*)R1;                       // 16 MB
  float*          D1   = (float*)(R1 + (size_t)NPTS*NPTS*4); // second 16 MB (dead until X_bf)
  unsigned short* X_bf = (unsigned short*)R1;
  unsigned short* ctx_bf = (unsigned short*)R2;
  float*          Y    = (float*)R2;

  // one-time prep (fused: weights, feat_bf, xyz norms, feature row norms)
  pack_all<<<(N_WTX+N_WFFN+N_WFC+N_FEAT+N_PP+N_NRM)/256, 256, 0, stream>>>(
      qW,kW,vW,rW,qb,kb,vb,rb, ffnW, fcW, feature, base_xyz,
      WT_x, bcat, WT_ffn, WT_fc, feat_bf, ppxyz, nrm);

  knn_xyz_kernel<<<ROWS/4, 256, 0, stream>>>(xyz, base_xyz, ppxyz, idx0);

  // per-pair feature-distance (frozen bit-exact, symmetry-halved, triangular grid,
  // both batches of the pair in one launch via grid.z) + paired top-k
  for (int pair = 0; pair < 2; ++pair){
    dist_feat_kernel<<<dim3(2080, 1, 2), 256, 0, stream>>>(feature, nrm, D0, D1, pair);
    topk_row_pair<<<(2*NPTS)/4, 256, 0, stream>>>(D0, D1, idx1, pair*2);
  }

  // X[8192][2048] bf16 = feat_bf @ WT_x^T, both branches in one launch
  mfma_gemm<unsigned short><<<dim3(2048/64, ROWS/64, 1), 256, 0, stream>>>(
      feat_bf, WT_x, bcat, X_bf, 2048, CIN, 0, 0, 0, 0);

  // attention: both branches, one launch
  attn_kernel<<<dim3(ROWS/2, 2), 256, 0, stream>>>(X_bf, idx0, idx1, ctx_bf);

  // res BN partials (slots 0,1)
  bnx_partial<<<dim3(32, 2), 256, 0, stream>>>(X_bf, partial);

  // ffn GEMM: F_bf[i] = ctx_bf[i] @ ffnW_i + ffnb_i  (batched grid.z=2)
  mfma_gemm<unsigned short><<<dim3(COUT/64, ROWS/64, 2), 256, 0, stream>>>(
      ctx_bf, WT_ffn, ffnb, F_bf, COUT, COUT,
      (size_t)ROWS*COUT, (size_t)COUT*COUT, COUT, (size_t)ROWS*COUT);

  // ffn BN partials (slots 2,3) then ONE final for slots 0-3
  bnf_partial<<<dim3(32, 2), 256, 0, stream>>>(F_bf, partial + (size_t)2*32*512);
  bn_final2<<<dim3(1, 4), 256, 0, stream>>>(partial, stats);          // slots 0..3

  build_m_kernel<<<ROWS, 256, 0, stream>>>(X_bf, F_bf, stats,
      res_gamma, res_beta, ffn_gamma, ffn_beta, Mmat_bf);

  // fc: Y = Mmat @ fcW + fcb  (ctx region dead -> Y)
  mfma_gemm<float><<<dim3(COUT/64, ROWS/64, 1), 256, 0, stream>>>(
      Mmat_bf, WT_fc, fcb, Y, COUT, 512, 0, 0, 0, 0);

  bny_partial<<<32, 256, 0, stream>>>(Y, partial);
  bn_final2<<<dim3(1, 1), 256, 0, stream>>>(partial, stats + 4*512);  // slot 4

  final_kernel<<<ROWS, 256, 0, stream>>>(Y, stats + 4*512, fc_gamma, fc_beta, out);
}

// Round 12
// 395.593 us; speedup vs baseline: 1.1114x; 1.0019x over previous
//
#include <hip/hip_runtime.h>
#include <hip/hip_bf16.h>

typedef __hip_bfloat16 bf16;
typedef __attribute__((ext_vector_type(8))) short short8;
typedef __attribute__((ext_vector_type(4))) float f32x4;

#define ROWS 8192   // B*N
#define NPTS 2048
#define CIN  128
#define COUT 256
#define KNN  32
#define PAD  132    // dist_feat LDS leading dim: 16B-aligned rows -> ds_read_b128 (PAD=129 regressed, R13)

__device__ inline float lrelu(float x){ return x >= 0.f ? x : 0.2f*x; }
__device__ inline unsigned short f2bf(float x){
  bf16 h = __float2bfloat16(x);
  return *(unsigned short*)&h;
}
__device__ inline float bf2f(unsigned short u){ return __uint_as_float((unsigned)u << 16); }
__device__ inline void stc(float* p, float v){ *p = v; }
__device__ inline void stc(unsigned short* p, float v){ *p = f2bf(v); }

// ---------------- fused one-time prep: WT_x, bcat, WT_ffn, WT_fc, feat_bf, pp(base_xyz), rownorm ----------------
#define N_WTX   (2048*CIN)          // 262144
#define N_WFFN  (2*COUT*COUT)       // 131072
#define N_WFC   (COUT*512)          // 131072
#define N_FEAT  (ROWS*CIN)          // 1048576
#define N_PP    8192                // 4 batches x 2048 base-point norms
#define N_NRM   8192                // feature row norms (one thread per row, frozen chain)
__global__ __launch_bounds__(256) void pack_all(
    const float* qW, const float* kW, const float* vW, const float* rW,
    const float* qb, const float* kb, const float* vb, const float* rb,
    const float* ffnW, const float* fcW, const float* feature, const float* base_xyz,
    unsigned short* WT_x, float* bcat, unsigned short* WT_ffn,
    unsigned short* WT_fc, unsigned short* feat_bf, float* ppxyz, float* nrm){
  int t = blockIdx.x*256 + threadIdx.x;
  if (t < N_WTX){
    int c = t >> 7, r = t & 127;
    int g = c >> 8, i = g >> 2, tt = g & 3, cc = c & 255;
    const float* W = (tt==0?qW: tt==1?kW: tt==2?vW: rW) + (size_t)i*CIN*COUT;
    WT_x[t] = f2bf(W[r*COUT + cc]);
    if (r == 0){
      const float* bb = (tt==0?qb: tt==1?kb: tt==2?vb: rb) + i*COUT;
      bcat[c] = bb[cc];
    }
  } else if (t < N_WTX + N_WFFN){
    int u = t - N_WTX;
    int i = u >> 16, n = (u >> 8) & 255, k = u & 255;
    WT_ffn[u] = f2bf(ffnW[(size_t)i*65536 + k*256 + n]);
  } else if (t < N_WTX + N_WFFN + N_WFC){
    int u = t - N_WTX - N_WFFN;
    int n = u >> 9, k = u & 511;
    WT_fc[u] = f2bf(fcW[(size_t)k*256 + n]);
  } else if (t < N_WTX + N_WFFN + N_WFC + N_FEAT){
    int u = t - N_WTX - N_WFFN - N_WFC;
    feat_bf[u] = f2bf(feature[u]);
  } else if (t < N_WTX + N_WFFN + N_WFC + N_FEAT + N_PP){
    // base-point norms, frozen chain
    int u = t - N_WTX - N_WFFN - N_WFC - N_FEAT;
    float p0 = base_xyz[(size_t)u*3+0];
    float p1 = base_xyz[(size_t)u*3+1];
    float p2 = base_xyz[(size_t)u*3+2];
    ppxyz[u] = __fadd_rn(__fadd_rn(__fmul_rn(p0,p0), __fmul_rn(p1,p1)), __fmul_rn(p2,p2));
  } else {
    // feature row norms (frozen: numpy AVX512 pairwise)
    int row = t - N_WTX - N_WFFN - N_WFC - N_FEAT - N_PP;   // exactly N_NRM
    const float* f = feature + (size_t)row*CIN;
    float L[16];
    #pragma unroll
    for (int l = 0; l < 16; ++l){
      float x0 = __fmul_rn(f[l],     f[l]);
      float x1 = __fmul_rn(f[16+l],  f[16+l]);
      float x2 = __fmul_rn(f[32+l],  f[32+l]);
      float x3 = __fmul_rn(f[48+l],  f[48+l]);
      float x4 = __fmul_rn(f[64+l],  f[64+l]);
      float x5 = __fmul_rn(f[80+l],  f[80+l]);
      float x6 = __fmul_rn(f[96+l],  f[96+l]);
      float x7 = __fmul_rn(f[112+l], f[112+l]);
      L[l] = __fadd_rn(
          __fadd_rn(__fadd_rn(x0,x1), __fadd_rn(x2,x3)),
          __fadd_rn(__fadd_rn(x4,x5), __fadd_rn(x6,x7)));
    }
    float T2[4];
    #pragma unroll
    for (int i = 0; i < 4; ++i)
      T2[i] = __fadd_rn(__fadd_rn(L[i], L[i+8]), __fadd_rn(L[i+4], L[i+12]));
    nrm[row] = __fadd_rn(__fadd_rn(T2[0], T2[2]), __fadd_rn(T2[1], T2[3]));
  }
}

// ---------------- wave-parallel top-32, 32-bit keys, MODE1 ownership ----------------
// m = lane*32 + slot (lane owns 32 CONTIGUOUS indices, keys in registers).
// Key = monotone u32 transform of fp32 distance. Exact numpy tie-order (lowest m among
// equal dists) decomposes: ballot lowest LANE with min ✓ then owner's lowest SLOT ✓.
// Reduce = 4x v_min_u32+row_shr DPP (row_bcast is REMOVED on CDNA2+), 4x readlane +
// scalar min, ballot+ctz for owner. Sentinel 0xFFFFFFFF unreachable for finite inputs.
__device__ inline unsigned dxf(float d){
  unsigned u = __float_as_uint(d);
  return (u & 0x80000000u) ? ~u : (u | 0x80000000u);
}
__device__ inline unsigned umin32(unsigned a, unsigned b){ return a < b ? a : b; }

#define DPP_ROW_SHR1    0x111
#define DPP_ROW_SHR2    0x112
#define DPP_ROW_SHR4    0x114
#define DPP_ROW_SHR8    0x118

template<int CTRL>
__device__ inline unsigned dpp_umin_step(unsigned v){
  // bound_ctrl=false, old=own value: invalid lanes keep own -> min(v,v)=v
  unsigned s = (unsigned)__builtin_amdgcn_update_dpp((int)v, (int)v, CTRL, 0xF, 0xF, false);
  return s < v ? s : v;
}

#define TOPK32_CASE(G)                                                   \
  {                                                                      \
    int jw = 7;                                                          \
    _Pragma("unroll")                                                    \
    for (int j = 7; j >= 0; --j) if (k[G*8+j] == minv) jw = j;           \
    slot = G*8 + jw;                                                     \
    _Pragma("unroll")                                                    \
    for (int j = 0; j < 8; ++j) if (j == jw) k[G*8+j] = ~0u;             \
    unsigned nm = k[G*8];                                                \
    _Pragma("unroll")                                                    \
    for (int j = 1; j < 8; ++j) nm = umin32(nm, k[G*8+j]);               \
    g[G] = nm;                                                           \
  }

__device__ inline void wave_topk32_u32(unsigned* k, int lane, int* out){
  unsigned g[4];
  #pragma unroll
  for (int gi = 0; gi < 4; ++gi){
    unsigned m = k[gi*8];
    #pragma unroll
    for (int j = 1; j < 8; ++j) m = umin32(m, k[gi*8+j]);
    g[gi] = m;
  }
  unsigned outv = 0;
  for (int r = 0; r < KNN; ++r){
    unsigned lm = umin32(umin32(g[0], g[1]), umin32(g[2], g[3]));  // lane's own min
    unsigned m = lm;
    m = dpp_umin_step<DPP_ROW_SHR1>(m);
    m = dpp_umin_step<DPP_ROW_SHR2>(m);
    m = dpp_umin_step<DPP_ROW_SHR4>(m);
    m = dpp_umin_step<DPP_ROW_SHR8>(m);
    unsigned b0 = (unsigned)__builtin_amdgcn_readlane((int)m, 15);
    unsigned b1 = (unsigned)__builtin_amdgcn_readlane((int)m, 31);
    unsigned b2 = (unsigned)__builtin_amdgcn_readlane((int)m, 47);
    unsigned b3 = (unsigned)__builtin_amdgcn_readlane((int)m, 63);
    unsigned minv = umin32(umin32(b0, b1), umin32(b2, b3));        // wave-uniform
    unsigned long long ball = __ballot(lm == minv);
    int owner = (int)__builtin_ctzll(ball);                        // lowest tied lane = lowest m
    int slot = 0;
    if (owner == lane){
      int gw = (g[0]==minv) ? 0 : (g[1]==minv) ? 1 : (g[2]==minv) ? 2 : 3;  // lowest group
      if      (gw == 0) TOPK32_CASE(0)
      else if (gw == 1) TOPK32_CASE(1)
      else if (gw == 2) TOPK32_CASE(2)
      else              TOPK32_CASE(3)
    }
    int slotw = __builtin_amdgcn_readlane(slot, owner);            // wave-uniform
    unsigned wm = (unsigned)(owner*32 + slotw);
    outv = (lane == r) ? wm : outv;                                // lane r captures winner r
  }
  if (lane < KNN) out[lane] = (int)outv;
}

// ---------------- xyz KNN distance key (frozen: numpy-faithful fp32, bit-exact) ----------------
__device__ inline unsigned dkey_xyz(float qq, float q0, float q1, float q2,
                                    float p0, float p1, float p2, float pp){
  float dot = __fmul_rn(q0,p0);
  dot = __fadd_rn(dot, __fmul_rn(q1,p1));
  dot = __fadd_rn(dot, __fmul_rn(q2,p2));
  float d = __fsub_rn(__fadd_rn(qq, pp), __fmul_rn(2.f, dot));
  return dxf(d);
}

// ---------------- FAT KERNEL: dist_feat (pair) + optional xyz-KNN co-scheduled ----------------
// R12: knn_xyz (VALU-bound, LDS-free) and dist_feat (LDS-read-bound) are independent;
// same-stream launches serialize, so merge them into one launch with interleaved block
// dispatch (bid%3==0 -> knn) so each CU runs a mix and the pipes overlap.
// Both bodies byte-identical to R11 -> bit-identical outputs. knn_total=0 => dist-only.
// dist: triangular decode (2080 tiles/batch), batch = dist_idx/2080 within pair.
__global__ __launch_bounds__(256) void dist_knn_kernel(
    const float* feature, const float* nrm4, float* D0, float* D1, int pair,
    const float* xyz, const float* base, const float* ppxyz, int* idx0, int knn_total){
  __shared__ float Aq[32*PAD];
  __shared__ float Bm[32*PAD];
  int bid = blockIdx.x;
  bool is_knn = (bid < 3*knn_total) && (bid % 3 == 0);
  if (is_knn){
    // ---- xyz KNN body (R11 knn_xyz_kernel verbatim; 4 queries/block, 1 per wave) ----
    int wave = threadIdx.x >> 6;
    int lane = threadIdx.x & 63;
    int qid = (bid/3)*4 + wave;
    int b = qid >> 11;
    float q0 = xyz[(size_t)qid*3+0];
    float q1 = xyz[(size_t)qid*3+1];
    float q2 = xyz[(size_t)qid*3+2];
    float qq = __fadd_rn(__fadd_rn(__fmul_rn(q0,q0), __fmul_rn(q1,q1)), __fmul_rn(q2,q2));
    const float4* p4 = (const float4*)(base + (size_t)b*NPTS*3 + (size_t)lane*96);
    const float4* n4 = (const float4*)(ppxyz + (size_t)b*NPTS + (size_t)lane*32);
    unsigned k[32];
    #pragma unroll
    for (int c = 0; c < 8; ++c){
      float4 f0 = p4[c*3+0];   // x0 y0 z0 x1
      float4 f1 = p4[c*3+1];   // y1 z1 x2 y2
      float4 f2 = p4[c*3+2];   // z2 x3 y3 z3
      float4 pn = n4[c];
      k[c*4+0] = dkey_xyz(qq,q0,q1,q2, f0.x, f0.y, f0.z, pn.x);
      k[c*4+1] = dkey_xyz(qq,q0,q1,q2, f0.w, f1.x, f1.y, pn.y);
      k[c*4+2] = dkey_xyz(qq,q0,q1,q2, f1.z, f1.w, f2.x, pn.z);
      k[c*4+3] = dkey_xyz(qq,q0,q1,q2, f2.y, f2.z, f2.w, pn.w);
    }
    wave_topk32_u32(k, lane, idx0 + (size_t)qid*KNN);
    return;
  }
  // ---- dist_feat body (R11 verbatim; dist_idx strips out interleaved knn blocks) ----
  int sub = (bid < 3*knn_total) ? (bid+2)/3 : knn_total;
  int dist_idx = bid - sub;                 // 0..4159
  int z = dist_idx >= 2080;
  int t0 = dist_idx - z*2080;
  const float* fb  = feature + (size_t)(pair*2 + z)*NPTS*CIN;
  const float* nrm = nrm4    + (size_t)(pair*2 + z)*NPTS;
  float* D = z ? D1 : D0;
  // triangular decode: t0 = v*(v+1)/2 + u, u <= v  (nb = u*32 <= mb = v*32)
  int v = (int)((__fsqrt_rn(8.f*(float)t0 + 1.f) - 1.f)*0.5f);
  while ((v+1)*(v+2)/2 <= t0) ++v;
  while (v*(v+1)/2 > t0) --v;
  int u = t0 - v*(v+1)/2;
  int nb = u*32, mb = v*32;
  int t = threadIdx.x;
  {
    int r = t >> 3, c16 = (t & 7) << 4;
    const float* an = fb + (size_t)(nb + r)*CIN + c16;
    const float* bm = fb + (size_t)(mb + r)*CIN + c16;
    #pragma unroll
    for (int j = 0; j < 4; ++j){
      *(float4*)&Aq[r*PAD + c16 + 4*j] = *(const float4*)&an[4*j];
      *(float4*)&Bm[r*PAD + c16 + 4*j] = *(const float4*)&bm[4*j];
    }
  }
  __syncthreads();
  int tx = t & 15, ty = t >> 4;
  const float* qa0 = &Aq[(ty     )*PAD];
  const float* qa1 = &Aq[(ty + 16)*PAD];
  const float* ma0 = &Bm[(tx     )*PAD];
  const float* ma1 = &Bm[(tx + 16)*PAD];
  float P[2][2][16];
  // chain order over segments: 48,32,16,0,112,96,80,64 (first = mul)
  #pragma unroll
  for (int l = 0; l < 16; ++l){
    float a0 = qa0[48+l], a1 = qa1[48+l], b0 = ma0[48+l], b1 = ma1[48+l];
    P[0][0][l] = __fmul_rn(a0,b0); P[0][1][l] = __fmul_rn(a0,b1);
    P[1][0][l] = __fmul_rn(a1,b0); P[1][1][l] = __fmul_rn(a1,b1);
  }
  const int segs[7] = {32,16,0,112,96,80,64};
  #pragma unroll
  for (int s = 0; s < 7; ++s){
    int off = segs[s];
    #pragma unroll
    for (int l = 0; l < 16; ++l){
      float a0 = qa0[off+l], a1 = qa1[off+l], b0 = ma0[off+l], b1 = ma1[off+l];
      P[0][0][l] = __fmaf_rn(a0,b0,P[0][0][l]); P[0][1][l] = __fmaf_rn(a0,b1,P[0][1][l]);
      P[1][0][l] = __fmaf_rn(a1,b0,P[1][0][l]); P[1][1][l] = __fmaf_rn(a1,b1,P[1][1][l]);
    }
  }
  float val[2][2];
  #pragma unroll
  for (int i = 0; i < 2; ++i){
    int n = nb + ty + 16*i;
    float nn = nrm[n];
    #pragma unroll
    for (int j = 0; j < 2; ++j){
      float T2[4];
      #pragma unroll
      for (int q = 0; q < 4; ++q)
        T2[q] = __fadd_rn(__fadd_rn(P[i][j][q], P[i][j][q+8]), __fadd_rn(P[i][j][q+4], P[i][j][q+12]));
      float dot = __fadd_rn(__fadd_rn(T2[0], T2[2]), __fadd_rn(T2[1], T2[3]));
      int m = mb + tx + 16*j;
      float vv = __fsub_rn(__fadd_rn(nn, nrm[m]), __fmul_rn(2.f, dot));
      val[i][j] = vv;
      D[(size_t)n*NPTS + m] = vv;
    }
  }
  // mirror tile: stage transposed in LDS (reuse Aq after all reads done), write coalesced
  __syncthreads();
  float* Tt = Aq;   // [32][33]
  #pragma unroll
  for (int i = 0; i < 2; ++i)
    #pragma unroll
    for (int j = 0; j < 2; ++j)
      Tt[(tx + 16*j)*33 + (ty + 16*i)] = val[i][j];
  __syncthreads();
  #pragma unroll
  for (int i = 0; i < 2; ++i)
    #pragma unroll
    for (int j = 0; j < 2; ++j)
      D[(size_t)(mb + ty + 16*i)*NPTS + (nb + tx + 16*j)] = Tt[(ty + 16*i)*33 + (tx + 16*j)];
}

// ---------------- feature top-k: float4 loads, m = lane*32 + j (MODE1 contiguous) ----------------
// TWO batches per launch (D0,D1 ping-pong buffers) -> 1024 blocks (2x TLP), 4 launches -> 2.
__global__ __launch_bounds__(256, 6) void topk_row_pair(const float* D0, const float* D1,
                                                        int* idx_out, int batch_base){
  int wave = threadIdx.x >> 6;
  int lane = threadIdx.x & 63;
  int ng = blockIdx.x*4 + wave;          // 0..4095
  int bb = ng >> 11;                     // 0 or 1 (local batch)
  int n  = ng & (NPTS-1);
  const float* D = bb ? D1 : D0;
  const float* src = D + (size_t)n*NPTS + lane*32;
  unsigned k[32];
  #pragma unroll
  for (int i = 0; i < 8; ++i){
    float4 v = *(const float4*)&src[i*4];
    k[i*4+0] = dxf(v.x);
    k[i*4+1] = dxf(v.y);
    k[i*4+2] = dxf(v.z);
    k[i*4+3] = dxf(v.w);
  }
  wave_topk32_u32(k, lane, idx_out + ((size_t)(batch_base + bb)*NPTS + n)*KNN);
}

// ---------------- MFMA GEMM (batched via grid.z): C = bf16(A)[M,K] @ bf16(B^T)[N,K] + bias ----------------
template<typename CT>
__global__ __launch_bounds__(256) void mfma_gemm(const unsigned short* __restrict__ A,
                                                 const unsigned short* __restrict__ Bt,
                                                 const float* __restrict__ bias,
                                                 CT* __restrict__ C, int N, int K,
                                                 size_t sA, size_t sB, size_t sBias, size_t sC){
  int z = blockIdx.z;
  A += (size_t)z*sA; Bt += (size_t)z*sB; bias += (size_t)z*sBias; C += (size_t)z*sC;
  __shared__ unsigned short As[64*40];
  __shared__ unsigned short Bs[64*40];
  int nb = blockIdx.x*64, mb = blockIdx.y*64;
  int t = threadIdx.x;
  int wave = t >> 6, lane = t & 63;
  int m16 = lane & 15, quad = lane >> 4;
  f32x4 acc[4];
  #pragma unroll
  for (int s = 0; s < 4; ++s) acc[s] = (f32x4){0.f, 0.f, 0.f, 0.f};
  int srow = t >> 2, skseg = (t & 3) << 3;
  for (int kt = 0; kt < K; kt += 32){
    __syncthreads();
    *(uint4*)&As[srow*40 + skseg] = *(const uint4*)&A [(size_t)(mb + srow)*K + kt + skseg];
    *(uint4*)&Bs[srow*40 + skseg] = *(const uint4*)&Bt[(size_t)(nb + srow)*K + kt + skseg];
    __syncthreads();
    short8 a = *(const short8*)&As[(wave*16 + m16)*40 + quad*8];
    #pragma unroll
    for (int s = 0; s < 4; ++s){
      short8 b = *(const short8*)&Bs[(s*16 + m16)*40 + quad*8];
      acc[s] = __builtin_amdgcn_mfma_f32_16x16x32_bf16(a, b, acc[s], 0, 0, 0);
    }
  }
  #pragma unroll
  for (int s = 0; s < 4; ++s){
    int col = nb + s*16 + m16;
    float bv = bias[col];
    #pragma unroll
    for (int r = 0; r < 4; ++r){
      int row = mb + wave*16 + quad*4 + r;
      stc(&C[(size_t)row*N + col], acc[s][r] + bv);
    }
  }
}

// ---------------- attention: bf16 X [8192][2048], both branches via grid.y; ushort2 gathers ----------------
// Validated optimum (R9/R11): 3 loops, max-subtract, exp cache, VGPR-addressed gathers.
// A/B history: merged loop regressed (R8); saddr gathers regressed (R10).
__global__ __launch_bounds__(256) void attn_kernel(const unsigned short* X,
                                                   const int* idx0, const int* idx1,
                                                   unsigned short* ctx){
  int i = blockIdx.y;
  const int* ip = (i == 0 ? idx0 : idx1);
  int local = threadIdx.x & 127;
  int r     = threadIdx.x >> 7;
  int bn    = blockIdx.x*2 + r;
  int b     = bn >> 11;
  __shared__ int jr[2][KNN];
  if (local < KNN) jr[r][local] = (b << 11) + ip[(size_t)bn*KNN + local];
  __syncthreads();
  const ushort2* X2 = (const ushort2*)X;
  size_t boff = (size_t)i*512 + local;
  ushort2 q2 = X2[(size_t)bn*1024 + boff];
  float qx = bf2f(q2.x), qy = bf2f(q2.y);
  float ex[KNN], ey[KNN];
  float mx = -3.4e38f, my = -3.4e38f;
  #pragma unroll
  for (int k = 0; k < KNN; ++k){
    ushort2 k2 = X2[(size_t)jr[r][k]*1024 + boff + 128];
    ex[k] = (qx - bf2f(k2.x)) * 0.0625f;
    ey[k] = (qy - bf2f(k2.y)) * 0.0625f;
    mx = fmaxf(mx, ex[k]);
    my = fmaxf(my, ey[k]);
  }
  float sx = 0.f, sy = 0.f;
  #pragma unroll
  for (int k = 0; k < KNN; ++k){
    ex[k] = __expf(ex[k] - mx);
    ey[k] = __expf(ey[k] - my);
    sx += ex[k];
    sy += ey[k];
  }
  float ix = 1.f / sx, iy = 1.f / sy;
  float bx = -3.4e38f, by = -3.4e38f;
  #pragma unroll
  for (int k = 0; k < KNN; ++k){
    ushort2 v2 = X2[(size_t)jr[r][k]*1024 + boff + 256];
    float ax = ex[k]*ix - 1.0f;
    float ay = ey[k]*iy - 1.0f;
    bx = fmaxf(bx, ax*bf2f(v2.x));
    by = fmaxf(by, ay*bf2f(v2.y));
  }
  ushort2 o; o.x = f2bf(bx); o.y = f2bf(by);
  ((ushort2*)ctx)[((size_t)i*ROWS + bn)*128 + local] = o;
}

// ---------------- BatchNorm stats (deterministic two-stage, batched over branches) ----------------
__global__ __launch_bounds__(256) void bnx_partial(const unsigned short* X, float* partial){
  int p = blockIdx.x, i = blockIdx.y, c = threadIdx.x;
  const unsigned short* base = X + (size_t)i*1024 + 768 + c;
  float s = 0.f, s2 = 0.f;
  for (int r = 0; r < 256; ++r){
    float v = bf2f(base[(size_t)(p*256 + r)*2048]);
    s += v; s2 += v*v;
  }
  partial[((size_t)i*32 + p)*512 + c]       = s;
  partial[((size_t)i*32 + p)*512 + 256 + c] = s2;
}

__global__ __launch_bounds__(256) void bnf_partial(const unsigned short* F, float* partial){
  int p = blockIdx.x, i = blockIdx.y, c = threadIdx.x;
  const unsigned short* base = F + (size_t)i*ROWS*COUT + c;
  float s = 0.f, s2 = 0.f;
  for (int r = 0; r < 256; ++r){
    float v = bf2f(base[(size_t)(p*256 + r)*COUT]);
    s += v; s2 += v*v;
  }
  partial[((size_t)i*32 + p)*512 + c]       = s;
  partial[((size_t)i*32 + p)*512 + 256 + c] = s2;
}

__global__ __launch_bounds__(256) void bny_partial(const float* Y, float* partial){
  int p = blockIdx.x, c = threadIdx.x;
  float s = 0.f, s2 = 0.f;
  for (int r = 0; r < 256; ++r){
    float v = Y[(size_t)(p*256 + r)*COUT + c];
    s += v; s2 += v*v;
  }
  partial[p*512 + c]       = s;
  partial[p*512 + 256 + c] = s2;
}

__global__ __launch_bounds__(256) void bn_final2(const float* partial, float* stats){
  int i = blockIdx.y, c = threadIdx.x;
  partial += (size_t)i*32*512;
  stats   += (size_t)i*512;
  float s = 0.f, s2 = 0.f;
  for (int p = 0; p < 32; ++p){ s += partial[p*512 + c]; s2 += partial[p*512 + 256 + c]; }
  float mean = s * (1.f/8192.f);
  float var  = s2 * (1.f/8192.f) - mean*mean;   // biased var
  stats[c]       = mean;
  stats[256 + c] = 1.f / sqrtf(var + 1e-5f);
}

// ---------------- m_i = leaky(bn_res(res)) + leaky(bn_ffn(F)) -> Mmat bf16, both branches ----------------
__global__ __launch_bounds__(256) void build_m_kernel(const unsigned short* X, const unsigned short* F,
    const float* stats, const float* gR, const float* bR, const float* gF, const float* bF,
    unsigned short* M){
  int bn = blockIdx.x, c = threadIdx.x;
  #pragma unroll
  for (int i = 0; i < 2; ++i){
    float r  = bf2f(X[(size_t)bn*2048 + i*1024 + 768 + c]);
    float rv = gR[i*COUT+c] * (r - stats[i*512+c]) * stats[i*512+256+c] + bR[i*COUT+c];
    rv = lrelu(rv);
    float f  = bf2f(F[(size_t)i*ROWS*COUT + (size_t)bn*COUT + c]);
    float fv = gF[i*COUT+c] * (f - stats[(2+i)*512+c]) * stats[(2+i)*512+256+c] + bF[i*COUT+c];
    fv = lrelu(fv);
    M[(size_t)bn*512 + i*COUT + c] = f2bf(rv + fv);
  }
}

__global__ __launch_bounds__(256) void final_kernel(const float* Y, const float* stats,
                                                    const float* g, const float* be, float* out){
  int bn = blockIdx.x, c = threadIdx.x;
  float y = Y[(size_t)bn*COUT + c];
  float v = g[c] * (y - stats[c]) * stats[256+c] + be[c];
  out[(size_t)bn*COUT + c] = lrelu(v);
}

extern "C" void kernel_launch(void* const* d_in, const int* in_sizes, int n_in,
                              void* d_out, int out_size, void* d_ws, size_t ws_size,
                              hipStream_t stream){
  const float* xyz      = (const float*)d_in[0];
  const float* base_xyz = (const float*)d_in[1];
  const float* feature  = (const float*)d_in[2];
  const float* qW = (const float*)d_in[3];
  const float* qb = (const float*)d_in[4];
  const float* kW = (const float*)d_in[5];
  const float* kb = (const float*)d_in[6];
  const float* vW = (const float*)d_in[7];
  const float* vb = (const float*)d_in[8];
  const float* rW = (const float*)d_in[9];
  const float* rb = (const float*)d_in[10];
  const float* res_gamma = (const float*)d_in[11];
  const float* res_beta  = (const float*)d_in[12];
  const float* ffnW = (const float*)d_in[13];
  const float* ffnb = (const float*)d_in[14];
  const float* ffn_gamma = (const float*)d_in[15];
  const float* ffn_beta  = (const float*)d_in[16];
  const float* fcW = (const float*)d_in[17];
  const float* fcb = (const float*)d_in[18];
  const float* fc_gamma = (const float*)d_in[19];
  const float* fc_beta  = (const float*)d_in[20];
  float* out = (float*)d_out;

  // ---- workspace plan (~62 MB, region reuse) ----
  char* ws = (char*)d_ws;
  size_t o = 0;
  auto alloc = [&](size_t bytes)->char*{
    char* p = ws + o;
    o += (bytes + 255) & ~(size_t)255;
    return p;
  };
  int*            idx0    = (int*)           alloc((size_t)ROWS*KNN*4);
  int*            idx1    = (int*)           alloc((size_t)ROWS*KNN*4);
  float*          nrm     = (float*)         alloc((size_t)ROWS*4);
  float*          ppxyz   = (float*)         alloc((size_t)N_PP*4);
  float*          bcat    = (float*)         alloc((size_t)2048*4);
  unsigned short* WT_x    = (unsigned short*)alloc((size_t)2048*CIN*2);
  unsigned short* WT_ffn  = (unsigned short*)alloc((size_t)2*COUT*COUT*2);
  unsigned short* WT_fc   = (unsigned short*)alloc((size_t)COUT*512*2);
  unsigned short* feat_bf = (unsigned short*)alloc((size_t)ROWS*CIN*2);
  float*          stats   = (float*)         alloc((size_t)5*512*4);
  float*          partial = (float*)         alloc((size_t)4*32*512*4);   // 4 slots (bnx 0-1, bnf 2-3)
  char*           R1      = alloc((size_t)ROWS*2048*2);   // 32 MB: D0+D1 fp32 (2x16MB) -> X bf16 [8192][2048]
  char*           R2      = alloc((size_t)ROWS*COUT*4);   //  8 MB: ctx_bf -> Y fp32
  unsigned short* Mmat_bf = (unsigned short*)alloc((size_t)ROWS*512*2);   // 8 MB
  unsigned short* F_bf    = (unsigned short*)alloc((size_t)2*ROWS*COUT*2);// 8 MB
  float*          D0   = (float*)R1;                       // 16 MB
  float*          D1   = (float*)(R1 + (size_t)NPTS*NPTS*4); // second 16 MB (dead until X_bf)
  unsigned short* X_bf = (unsigned short*)R1;
  unsigned short* ctx_bf = (unsigned short*)R2;
  float*          Y    = (float*)R2;

  // one-time prep (fused: weights, feat_bf, xyz norms, feature row norms)
  pack_all<<<(N_WTX+N_WFFN+N_WFC+N_FEAT+N_PP+N_NRM)/256, 256, 0, stream>>>(
      qW,kW,vW,rW,qb,kb,vb,rb, ffnW, fcW, feature, base_xyz,
      WT_x, bcat, WT_ffn, WT_fc, feat_bf, ppxyz, nrm);

  // pair 0: dist(batches 0,1) + ALL xyz-KNN co-scheduled (fat kernel, interleaved blocks)
  dist_knn_kernel<<<4160 + ROWS/4, 256, 0, stream>>>(
      feature, nrm, D0, D1, 0, xyz, base_xyz, ppxyz, idx0, ROWS/4);
  topk_row_pair<<<(2*NPTS)/4, 256, 0, stream>>>(D0, D1, idx1, 0);

  // pair 1: dist only
  dist_knn_kernel<<<4160, 256, 0, stream>>>(
      feature, nrm, D0, D1, 1, xyz, base_xyz, ppxyz, idx0, 0);
  topk_row_pair<<<(2*NPTS)/4, 256, 0, stream>>>(D0, D1, idx1, 2);

  // X[8192][2048] bf16 = feat_bf @ WT_x^T, both branches in one launch
  mfma_gemm<unsigned short><<<dim3(2048/64, ROWS/64, 1), 256, 0, stream>>>(
      feat_bf, WT_x, bcat, X_bf, 2048, CIN, 0, 0, 0, 0);

  // attention: both branches, one launch
  attn_kernel<<<dim3(ROWS/2, 2), 256, 0, stream>>>(X_bf, idx0, idx1, ctx_bf);

  // res BN partials (slots 0,1)
  bnx_partial<<<dim3(32, 2), 256, 0, stream>>>(X_bf, partial);

  // ffn GEMM: F_bf[i] = ctx_bf[i] @ ffnW_i + ffnb_i  (batched grid.z=2)
  mfma_gemm<unsigned short><<<dim3(COUT/64, ROWS/64, 2), 256, 0, stream>>>(
      ctx_bf, WT_ffn, ffnb, F_bf, COUT, COUT,
      (size_t)ROWS*COUT, (size_t)COUT*COUT, COUT, (size_t)ROWS*COUT);

  // ffn BN partials (slots 2,3) then ONE final for slots 0-3
  bnf_partial<<<dim3(32, 2), 256, 0, stream>>>(F_bf, partial + (size_t)2*32*512);
  bn_final2<<<dim3(1, 4), 256, 0, stream>>>(partial, stats);          // slots 0..3

  build_m_kernel<<<ROWS, 256, 0, stream>>>(X_bf, F_bf, stats,
      res_gamma, res_beta, ffn_gamma, ffn_beta, Mmat_bf);

  // fc: Y = Mmat @ fcW + fcb  (ctx region dead -> Y)
  mfma_gemm<float><<<dim3(COUT/64, ROWS/64, 1), 256, 0, stream>>>(
      Mmat_bf, WT_fc, fcb, Y, COUT, 512, 0, 0, 0, 0);

  bny_partial<<<32, 256, 0, stream>>>(Y, partial);
  bn_final2<<<dim3(1, 1), 256, 0, stream>>>(partial, stats + 4*512);  // slot 4

  final_kernel<<<ROWS, 256, 0, stream>>>(Y, stats + 4*512, fc_gamma, fc_beta, out);
}